// Round 5
// baseline (216.430 us; speedup 1.0000x reference)
//
#include <hip/hip_runtime.h>

// ---------------------------------------------------------------------------
// r[b,v] = sum_c (feats[b,c,v] - m[c,v]) / s[c,v] * weights[v,c] + bias[v]
// feats per scale k: GEMM  fmap_k (B*Ck x K=n^2)  @  prf_k^T (K x V)
// Fused epilogue: multiply feats tile by w'[c,v]=weights[v,c]/s[c,v], reduce
// over c in-block, atomicAdd into out (pre-initialized with the const term).
//
// R4 structure: 2-phase pipelined K-loop (reg-staged A prefetch + counted
// vmcnt + raw s_barrier), B pre-converted to swizzled bf16 tile-images in
// workspace and staged via global_load_lds(16B), T2 XOR-swizzled LDS.
// ---------------------------------------------------------------------------

typedef float f32x4 __attribute__((ext_vector_type(4)));
typedef __bf16 bf16x4 __attribute__((ext_vector_type(4)));
typedef __bf16 bf16x8 __attribute__((ext_vector_type(8)));

#define BM 128
#define BN 128
#define BK 64
#define V_DIM 512
#define C_TOT 960
#define B_DIM 128

// workspace layout (bytes)
#define WP_BYTES   1966080L                 // 960*512*4, 8192-aligned
#define BWS_BYTES  4390912L                 // 268 tiles * 128*64*2
#define WS_NEED_B  (WP_BYTES + BWS_BYTES)   // 6,356,992

// swizzled element index within a [128][64] bf16 tile (T2: cx ^= row&7)
static __device__ __forceinline__ int swz_idx(int row, int k) {
  return row * 64 + (((k >> 3) ^ (row & 7)) << 3) + (k & 7);
}

template <bool BWS>
__global__ __launch_bounds__(256, 3)
void fused_pool_readout(const float* __restrict__ fmap,   // [B*Ck, K] fp32
                        const float* __restrict__ prf,    // [V, K] fp32 (!BWS)
                        const __bf16* __restrict__ bws,   // swizzled B tiles (BWS)
                        const float* __restrict__ weights,// [V, C_TOT]
                        const float* __restrict__ fs,     // [C_TOT, V]
                        const float* __restrict__ wp,     // [C_TOT, V] or null
                        float* __restrict__ out,          // [B, V]
                        int Ck, int K, int Coff,
                        int nsteps_tot, int kchunks)
{
  __shared__ __bf16 lds_a[BM * BK];   // 16 KB, swizzled layout
  __shared__ __bf16 lds_b[BN * BK];   // 16 KB, swizzled layout

  const int tid  = threadIdx.x;
  const int lane = tid & 63;
  const int wid  = tid >> 6;
  const int wm   = wid >> 1;
  const int wn   = wid & 1;

  const long bm   = (long)blockIdx.y * BM;
  const int  bn_g = blockIdx.x;            // V-group 0..3
  const int  bn   = bn_g * BN;

  // split-K chunk [s0, send) of BK-steps
  const int z    = blockIdx.z;
  const int qb   = nsteps_tot / kchunks;
  const int rb   = nsteps_tot % kchunks;
  const int s0   = z * qb + (z < rb ? z : rb);
  const int send = s0 + qb + (z < rb ? 1 : 0);

  const bool K4 = ((K & 3) == 0);

  f32x4 acc[4][4];
#pragma unroll
  for (int i = 0; i < 4; ++i)
#pragma unroll
    for (int j = 0; j < 4; ++j)
      acc[i][j] = f32x4{0.f, 0.f, 0.f, 0.f};

  f32x4 areg[8], breg[8];

  // issue A-tile global loads for step ks into areg (no wait)
  auto issue_a = [&](int ks) {
#pragma unroll
    for (int i = 0; i < 8; ++i) {
      const int  chunk = tid + i * 256;
      const int  row   = chunk >> 4;
      const int  k0    = (chunk & 15) << 2;
      const long gk    = (long)ks * BK + k0;
      const float* p   = fmap + (bm + row) * (long)K + gk;
      f32x4 v = {0.f, 0.f, 0.f, 0.f};
      if (K4) {
        if (gk + 4 <= K) v = *(const f32x4*)p;
      } else {
        if (gk     < K) v[0] = p[0];
        if (gk + 1 < K) v[1] = p[1];
        if (gk + 2 < K) v[2] = p[2];
        if (gk + 3 < K) v[3] = p[3];
      }
      areg[i] = v;
    }
  };
  auto issue_b = [&](int ks) {   // fallback path only
#pragma unroll
    for (int i = 0; i < 8; ++i) {
      const int  chunk = tid + i * 256;
      const int  row   = chunk >> 4;
      const int  k0    = (chunk & 15) << 2;
      const long gk    = (long)ks * BK + k0;
      const float* p   = prf + (long)(bn + row) * K + gk;
      f32x4 v = {0.f, 0.f, 0.f, 0.f};
      if (K4) {
        if (gk + 4 <= K) v = *(const f32x4*)p;
      } else {
        if (gk     < K) v[0] = p[0];
        if (gk + 1 < K) v[1] = p[1];
        if (gk + 2 < K) v[2] = p[2];
        if (gk + 3 < K) v[3] = p[3];
      }
      breg[i] = v;
    }
  };

  // prologue: prefetch first step
  issue_a(s0);
  if constexpr (!BWS) issue_b(s0);

  for (int ks = s0; ks < send; ++ks) {
    // BARRIER-1: all waves done reading LDS from previous step's MFMA
    __builtin_amdgcn_sched_barrier(0);
    __builtin_amdgcn_s_barrier();
    __builtin_amdgcn_sched_barrier(0);

    if constexpr (BWS) {
      // stage B tile via global_load_lds: 4 x 1KB per wave, linear copy of
      // the pre-swizzled tile image (rule #21: inverse-swz source)
      const __bf16* src = bws + ((long)bn_g * nsteps_tot + ks) * (BN * BK);
#pragma unroll
      for (int i = 0; i < 4; ++i) {
        const int seg = wid * 4 + i;              // 0..15, 512 elems each
        __builtin_amdgcn_global_load_lds(
            (const __attribute__((address_space(1))) void*)(src + seg * 512 + lane * 8),
            (__attribute__((address_space(3))) void*)(&lds_b[seg * 512]),
            16, 0, 0);
      }
    }

    // convert + swizzled-write A(ks) (compiler inserts the vmcnt wait here;
    // areg was issued a full iteration ago)
#pragma unroll
    for (int i = 0; i < 8; ++i) {
      const int chunk = tid + i * 256;
      const int row   = chunk >> 4;
      const int k0    = (chunk & 15) << 2;
      const f32x4 v = areg[i];
      bf16x4 h = { (__bf16)v[0], (__bf16)v[1], (__bf16)v[2], (__bf16)v[3] };
      *(bf16x4*)&lds_a[swz_idx(row, k0)] = h;
    }
    if constexpr (!BWS) {
#pragma unroll
      for (int i = 0; i < 8; ++i) {
        const int chunk = tid + i * 256;
        const int row   = chunk >> 4;
        const int k0    = (chunk & 15) << 2;
        const f32x4 v = breg[i];
        bf16x4 h = { (__bf16)v[0], (__bf16)v[1], (__bf16)v[2], (__bf16)v[3] };
        *(bf16x4*)&lds_b[swz_idx(row, k0)] = h;
      }
    }

    // prefetch next step's A (and B) into regs — stays in flight across the
    // barrier (counted vmcnt below, never drained to 0 mid-loop)
    const bool hn = (ks + 1 < send);
    if (hn) {
      issue_a(ks + 1);
      if constexpr (!BWS) issue_b(ks + 1);
    }

    // drain LDS writes; for BWS also ensure the 4 B gl_lds (issued BEFORE the
    // 8 A prefetch loads) have landed while leaving the A prefetch in flight
    asm volatile("s_waitcnt lgkmcnt(0)" ::: "memory");
    if constexpr (BWS) {
      if (hn) asm volatile("s_waitcnt vmcnt(8)" ::: "memory");
      else    asm volatile("s_waitcnt vmcnt(0)" ::: "memory");
    }
    __builtin_amdgcn_sched_barrier(0);
    __builtin_amdgcn_s_barrier();
    __builtin_amdgcn_sched_barrier(0);

    // MFMA phase: swizzled conflict-free ds_read_b128 fragments
#pragma unroll
    for (int kc = 0; kc < 2; ++kc) {
      const int cx = kc * 4 + (lane >> 4);   // 16B chunk index 0..7
      bf16x8 af[4], bfr[4];
#pragma unroll
      for (int i = 0; i < 4; ++i) {
        const int r = wm * 64 + i * 16 + (lane & 15);
        af[i] = *(const bf16x8*)&lds_a[r * 64 + ((cx ^ (r & 7)) << 3)];
      }
#pragma unroll
      for (int j = 0; j < 4; ++j) {
        const int r = wn * 64 + j * 16 + (lane & 15);
        bfr[j] = *(const bf16x8*)&lds_b[r * 64 + ((cx ^ (r & 7)) << 3)];
      }
#pragma unroll
      for (int i = 0; i < 4; ++i)
#pragma unroll
        for (int j = 0; j < 4; ++j)
          acc[i][j] = __builtin_amdgcn_mfma_f32_16x16x32_bf16(af[i], bfr[j],
                                                              acc[i][j], 0, 0, 0);
    }
  }

  // ---- epilogue: per-wave 64x64 feats sub-tile; all 64 m-rows share one b.
  // C/D layout: frag row = (lane>>4)*4 + reg, frag col = lane&15   [m89]
  const long mbase = bm + wm * 64;
  const int  bidx  = (int)(mbase / Ck);
  const int  cbase = (int)(mbase % Ck) + Coff;
  const int  lrow  = ((lane >> 4) << 2);
  const int  lcol  = lane & 15;

#pragma unroll
  for (int j = 0; j < 4; ++j) {
    const int v = bn + wn * 64 + j * 16 + lcol;
    float s = 0.f;
#pragma unroll
    for (int i = 0; i < 4; ++i) {
      const int cg = cbase + i * 16 + lrow;
#pragma unroll
      for (int r = 0; r < 4; ++r) {
        float wfac;
        if (wp)  wfac = wp[(long)(cg + r) * V_DIM + v];
        else     wfac = weights[(long)v * C_TOT + cg + r]
                        / fs[(long)(cg + r) * V_DIM + v];
        s += acc[i][j][r] * wfac;
      }
    }
    s += __shfl_xor(s, 16);
    s += __shfl_xor(s, 32);
    if (lane < 16)
      atomicAdd(&out[(long)bidx * V_DIM + v], s);
  }
}

// ---- B pre-convert: fp32 prf -> swizzled bf16 tile images in workspace.
// Tile t within scale s at ws_b + (off_s + t)*8192 elems, t = g*nsteps + ks.
__global__ void prep_btile(const float* __restrict__ p0, const float* __restrict__ p1,
                           const float* __restrict__ p2, const float* __restrict__ p3,
                           __bf16* __restrict__ ws_b)
{
  int t = blockIdx.x;
  const float* prf; int K, ks, g; long base;
  if (t < 196)      { prf = p0; K = 3136;          g = t / 49; ks = t % 49; base = (long)t * 8192; }
  else if (t < 248) { t -= 196; prf = p1; K = 784; g = t / 13; ks = t % 13; base = (196L + t) * 8192; }
  else if (t < 264) { t -= 248; prf = p2; K = 196; g = t / 4;  ks = t % 4;  base = (248L + t) * 8192; }
  else              { t -= 264; prf = p3; K = 49;  g = t;      ks = 0;      base = (264L + t) * 8192; }
  const bool K4 = ((K & 3) == 0);
  const int tid = threadIdx.x;
#pragma unroll
  for (int i = 0; i < 8; ++i) {
    const int  chunk = tid + i * 256;
    const int  row   = chunk >> 4;
    const int  k0    = (chunk & 15) << 2;
    const long gk    = (long)ks * BK + k0;
    const float* sp  = prf + (long)(g * 128 + row) * K + gk;
    f32x4 v = {0.f, 0.f, 0.f, 0.f};
    if (K4) {
      if (gk + 4 <= K) v = *(const f32x4*)sp;
    } else {
      if (gk     < K) v[0] = sp[0];
      if (gk + 1 < K) v[1] = sp[1];
      if (gk + 2 < K) v[2] = sp[2];
      if (gk + 3 < K) v[3] = sp[3];
    }
    bf16x4 h = { (__bf16)v[0], (__bf16)v[1], (__bf16)v[2], (__bf16)v[3] };
    *(bf16x4*)&ws_b[base + swz_idx(row, k0)] = h;
  }
}

// wp[c*V+v] = weights[v*C+c] / fs[c*V+v]
__global__ void prep_wprime(const float* __restrict__ weights,
                            const float* __restrict__ fs,
                            float* __restrict__ wp)
{
  const int idx = blockIdx.x * 256 + threadIdx.x;
  if (idx >= C_TOT * V_DIM) return;
  const int c = idx >> 9;
  const int v = idx & (V_DIM - 1);
  wp[idx] = weights[(long)v * C_TOT + c] / fs[idx];
}

// out[b,v] = bias[v] - sum_c m[c,v]*w'[c,v]   (one block per v, parallel c)
__global__ void prep_off(const float* __restrict__ weights,
                         const float* __restrict__ bias,
                         const float* __restrict__ fm,
                         const float* __restrict__ fs,
                         const float* __restrict__ wp,   // may be null
                         float* __restrict__ out)
{
  __shared__ float red[4];
  const int v = blockIdx.x;
  const int t = threadIdx.x;
  float s = 0.f;
  for (int c = t; c < C_TOT; c += 256) {
    const long i = (long)c * V_DIM + v;
    const float w = wp ? wp[i] : weights[(long)v * C_TOT + c] / fs[i];
    s += fm[i] * w;
  }
#pragma unroll
  for (int o = 32; o; o >>= 1) s += __shfl_down(s, o);
  if ((t & 63) == 0) red[t >> 6] = s;
  __syncthreads();
  if (t < B_DIM) {
    const float off = bias[v] - (red[0] + red[1] + red[2] + red[3]);
    out[(long)t * V_DIM + v] = off;
  }
}

extern "C" void kernel_launch(void* const* d_in, const int* in_sizes, int n_in,
                              void* d_out, int out_size, void* d_ws, size_t ws_size,
                              hipStream_t stream)
{
  const float* fmap0   = (const float*)d_in[0];
  const float* prf0    = (const float*)d_in[1];
  const float* fmap1   = (const float*)d_in[2];
  const float* prf1    = (const float*)d_in[3];
  const float* fmap2   = (const float*)d_in[4];
  const float* prf2    = (const float*)d_in[5];
  const float* fmap3   = (const float*)d_in[6];
  const float* prf3    = (const float*)d_in[7];
  const float* weights = (const float*)d_in[8];
  const float* bias    = (const float*)d_in[9];
  const float* fm      = (const float*)d_in[10];
  const float* fs      = (const float*)d_in[11];
  float* out = (float*)d_out;

  const bool has_wp = ws_size >= (size_t)WP_BYTES;
  const bool has_b  = ws_size >= (size_t)WS_NEED_B;
  float*  wp   = has_wp ? (float*)d_ws : nullptr;
  __bf16* ws_b = has_b ? (__bf16*)((char*)d_ws + WP_BYTES) : nullptr;

  if (has_wp)
    prep_wprime<<<dim3((C_TOT * V_DIM + 255) / 256), dim3(256), 0, stream>>>(
        weights, fs, wp);
  if (has_b)
    prep_btile<<<dim3(268), dim3(256), 0, stream>>>(prf0, prf1, prf2, prf3, ws_b);

  prep_off<<<dim3(V_DIM), dim3(256), 0, stream>>>(weights, bias, fm, fs, wp, out);

  struct Scale { const float* fmap; const float* prf; long boff; int Ck, K, Coff, kchunks; };
  const Scale sc[4] = {
    {fmap0, prf0,    0L * 8192,  64, 56 * 56,   0, 3},  // 49 steps, 768 blocks
    {fmap1, prf1,  196L * 8192, 128, 28 * 28,  64, 2},  // 13 steps, 1024 blocks
    {fmap2, prf2,  248L * 8192, 256, 14 * 14, 192, 1},  //  4 steps, 1024 blocks
    {fmap3, prf3,  264L * 8192, 512,  7 * 7,  448, 1},  //  1 step,  2048 blocks
  };
  for (int k = 0; k < 4; ++k) {
    const int M = B_DIM * sc[k].Ck;
    const int nsteps = (sc[k].K + BK - 1) / BK;
    dim3 grid(V_DIM / BN, M / BM, sc[k].kchunks);
    if (has_b) {
      fused_pool_readout<true><<<grid, dim3(256), 0, stream>>>(
          sc[k].fmap, nullptr, ws_b + sc[k].boff, weights, fs, wp, out,
          sc[k].Ck, sc[k].K, sc[k].Coff, nsteps, sc[k].kchunks);
    } else {
      fused_pool_readout<false><<<grid, dim3(256), 0, stream>>>(
          sc[k].fmap, sc[k].prf, nullptr, weights, fs, wp, out,
          sc[k].Ck, sc[k].K, sc[k].Coff, nsteps, sc[k].kchunks);
    }
  }
}

// Round 6
// 199.873 us; speedup vs baseline: 1.0828x; 1.0828x over previous
//
#include <hip/hip_runtime.h>

// ---------------------------------------------------------------------------
// r[b,v] = sum_c (feats[b,c,v] - m[c,v]) / s[c,v] * weights[v,c] + bias[v]
// feats per scale k: GEMM  fmap_k (B*Ck x K=n^2)  @  prf_k^T (K x V)
// Fused epilogue: feats tile * w'[c,v]=weights[v,c]/s[c,v], c-reduced,
// atomicAdd into out (pre-initialized with off[v] = bias - sum m*w').
//
// R5 structure: ONE mega-kernel for all 4 scales (XCD-swizzled flat grid,
// split-K {6,3,2,1}); B pre-converted to MFMA-fragment-ordered bf16 in
// workspace and loaded straight to registers (no LDS, no gl_lds sync);
// A reg-prefetched 1 step deep into a double-buffered swizzled LDS tile
// with a single lgkm-drain raw barrier per K-step.
// ---------------------------------------------------------------------------

typedef float f32x4 __attribute__((ext_vector_type(4)));
typedef __bf16 bf16x4 __attribute__((ext_vector_type(4)));
typedef __bf16 bf16x8 __attribute__((ext_vector_type(8)));

#define BM 128
#define BN 128
#define BK 64
#define TILE_E (BM * BK)        // 8192 elems per staged tile
#define V_DIM 512
#define C_TOT 960
#define B_DIM 128

#define NBLK_TOT 7168           // 1536 + 1536 + 2048 + 2048  (=8*896)
#define PREP_BT 268
#define PREP_WP 1920
#define PREP_OFF 512
#define PREP_BLKS (PREP_BT + PREP_WP + PREP_OFF)

// workspace layout (bytes)
#define WP_BYTES 1966080L                   // 960*512*4
#define BT_BYTES (268L * TILE_E * 2)        // 4,390,912
#define WS_NEED  (WP_BYTES + BT_BYTES)

// T2 XOR-swizzle inside a [128][64] bf16 tile (16B-chunk granularity)
static __device__ __forceinline__ int swz_idx(int row, int k) {
  return row * 64 + (((k >> 3) ^ (row & 7)) << 3) + (k & 7);
}

template <bool BWS>
__global__ __launch_bounds__(256, 3)
void mega_gemm(const float* __restrict__ f0, const float* __restrict__ f1,
               const float* __restrict__ f2, const float* __restrict__ f3,
               const float* __restrict__ p0, const float* __restrict__ p1,
               const float* __restrict__ p2, const float* __restrict__ p3,
               const __bf16* __restrict__ bws,      // fragment-ordered B tiles
               const float* __restrict__ weights,   // [V, C_TOT]
               const float* __restrict__ fs,        // [C_TOT, V]
               const float* __restrict__ wp,        // [C_TOT, V] or null
               float* __restrict__ out)             // [B, V]
{
  __shared__ __bf16 lds[2 * TILE_E];   // 32 KB: double-buffered A tile

  const int tid  = threadIdx.x;
  const int lane = tid & 63;
  const int wid  = tid >> 6;
  const int wm   = wid >> 1;
  const int wn   = wid & 1;

  // bijective XCD-chunked swizzle (NBLK_TOT % 8 == 0): consecutive virtual
  // ids (= same A-panel, different N-tile) land on the SAME XCD's L2.
  const int bid = blockIdx.x;
  const int vid = (bid & 7) * (NBLK_TOT / 8) + (bid >> 3);

  int sc, loc;
  if (vid < 1536)      { sc = 0; loc = vid; }
  else if (vid < 3072) { sc = 1; loc = vid - 1536; }
  else if (vid < 5120) { sc = 2; loc = vid - 3072; }
  else                 { sc = 3; loc = vid - 5120; }

  const int KT[4]  = {3136, 784, 196, 49};
  const int NST[4] = {49, 13, 4, 1};
  const int KCH[4] = {6, 3, 2, 1};
  const int COF[4] = {0, 64, 192, 448};
  const int TB[4]  = {0, 196, 248, 264};
  const int CKA[4] = {64, 128, 256, 512};

  const float* fmap = sc == 0 ? f0 : sc == 1 ? f1 : sc == 2 ? f2 : f3;
  const float* prf  = sc == 0 ? p0 : sc == 1 ? p1 : sc == 2 ? p2 : p3;
  const int K      = KT[sc];
  const int nsteps = NST[sc];
  const int kch    = KCH[sc];
  const int Ck     = CKA[sc];
  const int Coff   = COF[sc];
  const int tbase  = TB[sc];

  // decode (x = N-tile fastest, then y = M-tile, then z = K-chunk);
  // M/BM = 128*Ck/128 = Ck tiles in y.
  const int x  = loc & 3;
  const int yz = loc >> 2;
  const int y  = yz % Ck;
  const int z  = yz / Ck;

  const long bm   = (long)y * BM;
  const int  bn_g = x;
  const int  bn   = x * BN;

  const int qb   = nsteps / kch, rb = nsteps % kch;
  const int s0   = z * qb + (z < rb ? z : rb);
  const int send = s0 + qb + (z < rb ? 1 : 0);
  const bool K4  = ((K & 3) == 0);

  f32x4 acc[4][4];
#pragma unroll
  for (int i = 0; i < 4; ++i)
#pragma unroll
    for (int j = 0; j < 4; ++j)
      acc[i][j] = f32x4{0.f, 0.f, 0.f, 0.f};

  f32x4 areg[8];

  auto issue_a = [&](int ks) {
#pragma unroll
    for (int i = 0; i < 8; ++i) {
      const int  chunk = tid + i * 256;
      const int  row   = chunk >> 4;
      const int  k0    = (chunk & 15) << 2;
      const long gk    = (long)ks * BK + k0;
      const float* p   = fmap + (bm + row) * (long)K + gk;
      f32x4 t = {0.f, 0.f, 0.f, 0.f};
      if (K4) {
        if (gk + 4 <= K) t = *(const f32x4*)p;
      } else {
        if (gk     < K) t[0] = p[0];
        if (gk + 1 < K) t[1] = p[1];
        if (gk + 2 < K) t[2] = p[2];
        if (gk + 3 < K) t[3] = p[3];
      }
      areg[i] = t;
    }
  };
  auto conv_write = [&](__bf16* buf) {
#pragma unroll
    for (int i = 0; i < 8; ++i) {
      const int chunk = tid + i * 256;
      const int row   = chunk >> 4;
      const int k0    = (chunk & 15) << 2;
      const f32x4 t   = areg[i];
      bf16x4 h = { (__bf16)t[0], (__bf16)t[1], (__bf16)t[2], (__bf16)t[3] };
      *(bf16x4*)&buf[swz_idx(row, k0)] = h;
    }
  };
  auto load_b = [&](int ks, bf16x8* br) {
    if constexpr (BWS) {
      const __bf16* tb = bws + (long)(tbase + bn_g * nsteps + ks) * TILE_E;
#pragma unroll
      for (int j = 0; j < 4; ++j)
#pragma unroll
        for (int kc = 0; kc < 2; ++kc)
          br[j * 2 + kc] =
              *(const bf16x8*)(tb + ((((wn * 4 + j) * 2 + kc) << 6) + lane) * 8);
    } else {
      // fallback: direct fp32 prf loads + convert (only if ws too small)
#pragma unroll
      for (int j = 0; j < 4; ++j)
#pragma unroll
        for (int kc = 0; kc < 2; ++kc) {
          const int row  = bn + wn * 64 + j * 16 + (lane & 15);
          const int kcol = ks * 64 + kc * 32 + ((lane >> 4) << 3);
          const float* sp = prf + (long)row * K + kcol;
          bf16x8 h;
#pragma unroll
          for (int e = 0; e < 8; ++e)
            h[e] = (__bf16)((kcol + e < K) ? sp[e] : 0.f);
          br[j * 2 + kc] = h;
        }
    }
  };

  // ---- prologue: fill buf0, prefetch A[s0+1]
  issue_a(s0);
  conv_write(lds);                       // compiler inserts the vmcnt wait
  if (s0 + 1 < send) issue_a(s0 + 1);
  asm volatile("s_waitcnt lgkmcnt(0)" ::: "memory");
  __builtin_amdgcn_sched_barrier(0);
  __builtin_amdgcn_s_barrier();
  __builtin_amdgcn_sched_barrier(0);

  // ---- main loop: ONE barrier per step, A dbuf, B straight to regs
  for (int ks = s0; ks < send; ++ks) {
    const int pp = (ks - s0) & 1;
    const __bf16* bufr = lds + pp * TILE_E;
    __bf16*       bufw = lds + (pp ^ 1) * TILE_E;

    bf16x8 breg[8];
    load_b(ks, breg);                    // VMEM issue early, used ~300cy later

    const bool hn = (ks + 1 < send);
    if (hn) {
      conv_write(bufw);                  // areg issued a full step ago
      if (ks + 2 < send) issue_a(ks + 2);
    }

#pragma unroll
    for (int kc = 0; kc < 2; ++kc) {
      const int cx = kc * 4 + (lane >> 4);
      bf16x8 af[4];
#pragma unroll
      for (int i = 0; i < 4; ++i) {
        const int r = wm * 64 + i * 16 + (lane & 15);
        af[i] = *(const bf16x8*)&bufr[r * 64 + ((cx ^ (r & 7)) << 3)];
      }
#pragma unroll
      for (int i = 0; i < 4; ++i)
#pragma unroll
        for (int j = 0; j < 4; ++j)
          acc[i][j] = __builtin_amdgcn_mfma_f32_16x16x32_bf16(
              af[i], breg[j * 2 + kc], acc[i][j], 0, 0, 0);
    }

    // drain LDS ops only; A prefetch stays in flight across the barrier
    asm volatile("s_waitcnt lgkmcnt(0)" ::: "memory");
    __builtin_amdgcn_sched_barrier(0);
    __builtin_amdgcn_s_barrier();
    __builtin_amdgcn_sched_barrier(0);
  }

  // ---- epilogue: per-wave 64x64 feats sub-tile, c-reduce, atomicAdd.
  // C/D layout: frag row = (lane>>4)*4 + reg, frag col = lane&15   [m89]
  const long mbase = bm + wm * 64;
  const int  bidx  = (int)(mbase / Ck);
  const int  cbase = (int)(mbase % Ck) + Coff;
  const int  lrow  = ((lane >> 4) << 2);
  const int  lcol  = lane & 15;

#pragma unroll
  for (int j = 0; j < 4; ++j) {
    const int v = bn + wn * 64 + j * 16 + lcol;
    float s = 0.f;
#pragma unroll
    for (int i = 0; i < 4; ++i) {
      const int cg = cbase + i * 16 + lrow;
#pragma unroll
      for (int r = 0; r < 4; ++r) {
        float wfac;
        if (wp)  wfac = wp[(long)(cg + r) * V_DIM + v];
        else     wfac = weights[(long)v * C_TOT + cg + r]
                        / fs[(long)(cg + r) * V_DIM + v];
        s += acc[i][j][r] * wfac;
      }
    }
    s += __shfl_xor(s, 16);
    s += __shfl_xor(s, 32);
    if (lane < 16)
      atomicAdd(&out[(long)bidx * V_DIM + v], s);
  }
}

// ---------------------------------------------------------------------------
// One prep launch: [0,268) B->fragment-ordered bf16 tiles; [268,2188) w';
// [2188,2700) out init with the constant term.
// ---------------------------------------------------------------------------
__global__ void prep_all(const float* __restrict__ p0, const float* __restrict__ p1,
                         const float* __restrict__ p2, const float* __restrict__ p3,
                         const float* __restrict__ weights,
                         const float* __restrict__ bias,
                         const float* __restrict__ fm,
                         const float* __restrict__ fs,
                         float* __restrict__ wp,      // may be null
                         __bf16* __restrict__ bt,     // may be null
                         float* __restrict__ out)
{
  __shared__ float red[4];
  const int blk = blockIdx.x;
  const int tid = threadIdx.x;

  if (blk < PREP_BT) {
    if (!bt) return;
    int t = blk; const float* prf; int K, g, ks;
    if (t < 196)      { prf = p0; K = 3136; g = t / 49; ks = t % 49; }
    else if (t < 248) { t -= 196; prf = p1; K = 784; g = t / 13; ks = t % 13; }
    else if (t < 264) { t -= 248; prf = p2; K = 196; g = t / 4;  ks = t % 4; }
    else              { t -= 264; prf = p3; K = 49;  g = t;      ks = 0; }
    const long base = (long)blk * TILE_E;
    // tile layout: chunk = (j2*2+kc)*64 + lane  ->  16B of B[row, k..k+7]
#pragma unroll
    for (int i = 0; i < 4; ++i) {
      const int chunk = tid + i * 256;          // 0..1023
      const int j2 = chunk >> 7;
      const int kc = (chunk >> 6) & 1;
      const int ln = chunk & 63;
      const int row  = g * 128 + j2 * 16 + (ln & 15);
      const int kcol = ks * 64 + kc * 32 + ((ln >> 4) << 3);
      const float* sp = prf + (long)row * K + kcol;
      bf16x8 h;
#pragma unroll
      for (int e = 0; e < 8; ++e)
        h[e] = (__bf16)((kcol + e < K) ? sp[e] : 0.f);
      *(bf16x8*)&bt[base + (long)chunk * 8] = h;
    }
  } else if (blk < PREP_BT + PREP_WP) {
    if (!wp) return;
    const int idx = (blk - PREP_BT) * 256 + tid;   // exactly 960*512
    const int c = idx >> 9;
    const int v = idx & (V_DIM - 1);
    wp[idx] = weights[(long)v * C_TOT + c] / fs[idx];
  } else {
    const int v = blk - (PREP_BT + PREP_WP);       // 0..511
    float s = 0.f;
    for (int c = tid; c < C_TOT; c += 256) {
      const long i = (long)c * V_DIM + v;
      s += fm[i] * weights[(long)v * C_TOT + c] / fs[i];
    }
#pragma unroll
    for (int o = 32; o; o >>= 1) s += __shfl_down(s, o);
    if ((tid & 63) == 0) red[tid >> 6] = s;
    __syncthreads();
    if (tid < B_DIM) {
      const float off = bias[v] - (red[0] + red[1] + red[2] + red[3]);
      out[(long)tid * V_DIM + v] = off;
    }
  }
}

extern "C" void kernel_launch(void* const* d_in, const int* in_sizes, int n_in,
                              void* d_out, int out_size, void* d_ws, size_t ws_size,
                              hipStream_t stream)
{
  const float* fmap0   = (const float*)d_in[0];
  const float* prf0    = (const float*)d_in[1];
  const float* fmap1   = (const float*)d_in[2];
  const float* prf1    = (const float*)d_in[3];
  const float* fmap2   = (const float*)d_in[4];
  const float* prf2    = (const float*)d_in[5];
  const float* fmap3   = (const float*)d_in[6];
  const float* prf3    = (const float*)d_in[7];
  const float* weights = (const float*)d_in[8];
  const float* bias    = (const float*)d_in[9];
  const float* fm      = (const float*)d_in[10];
  const float* fs      = (const float*)d_in[11];
  float* out = (float*)d_out;

  const bool has_wp = ws_size >= (size_t)WP_BYTES;
  const bool has_b  = ws_size >= (size_t)WS_NEED;
  float*  wp = has_wp ? (float*)d_ws : nullptr;
  __bf16* bt = has_b ? (__bf16*)((char*)d_ws + WP_BYTES) : nullptr;

  // 1) single prep launch: B fragment tiles + w' + out init
  prep_all<<<dim3(PREP_BLKS), dim3(256), 0, stream>>>(
      prf0, prf1, prf2, prf3, weights, bias, fm, fs, wp, bt, out);

  // 2) single mega GEMM+readout launch over all 4 scales
  if (has_b) {
    mega_gemm<true><<<dim3(NBLK_TOT), dim3(256), 0, stream>>>(
        fmap0, fmap1, fmap2, fmap3, prf0, prf1, prf2, prf3,
        bt, weights, fs, wp, out);
  } else {
    mega_gemm<false><<<dim3(NBLK_TOT), dim3(256), 0, stream>>>(
        fmap0, fmap1, fmap2, fmap3, prf0, prf1, prf2, prf3,
        nullptr, weights, fs, wp, out);
  }
}